// Round 11
// baseline (283.839 us; speedup 1.0000x reference)
//
#include <hip/hip_runtime.h>
#include <cstdint>

typedef unsigned short u16;
typedef short bf16x8 __attribute__((ext_vector_type(8)));
typedef float f32x4 __attribute__((ext_vector_type(4)));
typedef float f32x16 __attribute__((ext_vector_type(16)));
typedef unsigned int u32x2 __attribute__((ext_vector_type(2)));
typedef unsigned int u32x4 __attribute__((ext_vector_type(4)));

#define NB 4
#define SEQ 2048
#define DMODEL 1024
#define NHEADS 16
#define DHEAD 64
#define BHTOT (NB*NHEADS)   // 64
#define MROWS (NB*SEQ)      // 8192

__device__ __forceinline__ float bf2f(u16 u){
  union { unsigned int i; float f; } x; x.i = ((unsigned int)u)<<16; return x.f;
}
__device__ __forceinline__ u16 f2bf(float f){
  union { float f; unsigned int i; } x; x.f = f;
  unsigned int r = x.i + 0x7fffu + ((x.i>>16)&1u);
  return (u16)(r>>16);
}
// raw v_exp_f32 (r10 win: +13 us total vs libm exp2f's denormal-guard sequence)
__device__ __forceinline__ float fexp2(float x){
#if __has_builtin(__builtin_amdgcn_exp2f)
  return __builtin_amdgcn_exp2f(x);
#else
  return exp2f(x);
#endif
}

typedef const __attribute__((address_space(1))) unsigned int* gas_t;
typedef __attribute__((address_space(3))) unsigned int* las_t;
__device__ __forceinline__ void async_cp16(const void* g, void* l){
  __builtin_amdgcn_global_load_lds((gas_t)g, (las_t)l, 16, 0, 0);
}

// permlane32_swap: rows 32-63 of a exchange with rows 0-31 of b
__device__ __forceinline__ void plswap(unsigned int &a, unsigned int &b){
#if __has_builtin(__builtin_amdgcn_permlane32_swap)
  u32x2 r = __builtin_amdgcn_permlane32_swap(a, b, false, false);
  a = r[0]; b = r[1];
#else
  asm("v_permlane32_swap_b32 %0, %1" : "+v"(a), "+v"(b));
#endif
}

// ---------------- fp32 -> bf16 cast for BOTH weights (one launch) ----------------
__global__ __launch_bounds__(256) void cast2_kernel(const float* __restrict__ wa, u16* __restrict__ oa,
    const float* __restrict__ wb, u16* __restrict__ ob, int na4){
  int i = blockIdx.x*256 + threadIdx.x;
  const float* src; u16* dst; int j;
  if(i < na4){ src = wa; dst = oa; j = i; }
  else       { src = wb; dst = ob; j = i - na4; }
  float4 v = ((const float4*)src)[j];
  ushort4 o;
  o.x=f2bf(v.x); o.y=f2bf(v.y); o.z=f2bf(v.z); o.w=f2bf(v.w);
  ((ushort4*)dst)[j] = o;
}

// ---------------- LayerNorm: x fp32 -> h bf16 (f32 stats) ----------------
__global__ __launch_bounds__(256) void ln_kernel(const float* __restrict__ x, u16* __restrict__ h){
  int row = blockIdx.x;
  const float* xr = x + (size_t)row*DMODEL;
  u16* hr = h + (size_t)row*DMODEL;
  int t = threadIdx.x;
  float4 v = ((const float4*)xr)[t];
  float f0=v.x, f1=v.y, f2=v.z, f3=v.w;
  float s = f0+f1+f2+f3;
  float q = f0*f0+f1*f1+f2*f2+f3*f3;
  #pragma unroll
  for(int off=32; off; off>>=1){ s += __shfl_xor(s, off); q += __shfl_xor(q, off); }
  __shared__ float ss[4], sq[4];
  int wv = t>>6, lane = t&63;
  if(lane==0){ ss[wv]=s; sq[wv]=q; }
  __syncthreads();
  s = ss[0]+ss[1]+ss[2]+ss[3];
  q = sq[0]+sq[1]+sq[2]+sq[3];
  float mu  = s * (1.0f/DMODEL);
  float var = q * (1.0f/DMODEL) - mu*mu;
  float rs  = rsqrtf(var + 1e-8f);
  ushort4 o;
  o.x=f2bf((f0-mu)*rs); o.y=f2bf((f1-mu)*rs); o.z=f2bf((f2-mu)*rs); o.w=f2bf((f3-mu)*rs);
  ((ushort4*)hr)[t] = o;
}

// ---------------- GEMM: C[m,n] = sum_k A[m,k]*Bm[n,k], bf16 MFMA ----------------
// r11: 128x256 tile (was 128x128). r10 post-mortem: 128^2's arithmetic intensity
// (64 FLOP per staged byte) needs 53 B/cy/CU from L2 at MFMA peak vs the ~56 B/cy
// L2 ceiling -> staging-bandwidth-bound at MfmaUtil 29%. 128x256 = 85 FLOP/B ->
// 39 B/cy demand (30% headroom). 8 waves (2M x 4N), each wave the SAME 64x64
// sub-tile + epilogue code as the proven r7 kernel. 4-deep circular LDS (96 KB)
// with counted vmcnt (r9-proven race-free pattern; exact 6/3/0 tail waits):
// staging for tile tt+3 stays in flight across barriers, never drained.
// Pair-row XOR swizzle unchanged (r10: bank conflicts = 0).
#define BM 128
#define BN 256
#define BK 32

template<int MODE>
__global__ __launch_bounds__(512, 2) void gemm_bt(const u16* __restrict__ A, const u16* __restrict__ Bm,
    u16* __restrict__ Qb, u16* __restrict__ Kb, u16* __restrict__ Vtb, float* __restrict__ outf,
    int M, int N, int K){
  __shared__ u16 As[4][BM*BK];   // 4 x 8 KB
  __shared__ u16 Bs[4][BN*BK];   // 4 x 16 KB
  int t = threadIdx.x;
  int lane = t&63, wv = t>>6;
  int c = lane&15, g = lane>>4;
  int wm = wv>>2, wn = wv&3;     // 2 x 4 wave grid; per-wave 64x64 output
  int m0 = blockIdx.y*BM, n0 = blockIdx.x*BN;

  // staging: chunk cc -> pair-row p = cc>>3, slot j = cc&7, jsrc = j ^ (p&7);
  // global elem = (p*2 + (jsrc>>2))*K + (jsrc&3)*8. A: chunk t. B: chunks t, t+512
  // (t+512 differs only by +64 pair-rows; 64%8==0 so same jsrc, offset +128*K).
  int pA = t>>3, jA = t&7; int jsA = jA ^ (pA&7);
  size_t aoff = (size_t)(pA*2 + (jsA>>2))*K + (jsA&3)*8;
  const u16* Abase = A  + (size_t)m0*K;
  const u16* Bbase = Bm + (size_t)n0*K;

#define GSTAGE(TILE, BUF) { \
    size_t k_ = (size_t)(TILE)*BK; \
    async_cp16(Abase + k_ + aoff,            &As[BUF][t*8]); \
    async_cp16(Bbase + k_ + aoff,            &Bs[BUF][t*8]); \
    async_cp16(Bbase + k_ + aoff + 128*(size_t)K, &Bs[BUF][(t+512)*8]); }

  f32x4 acc[4][4] = {};
  int NK = K/BK;   // 32

  // prologue: 3 tiles in flight (3 VMEM insts per tile per thread -> 9 outstanding)
  GSTAGE(0, 0);
  GSTAGE(1, 1);
  GSTAGE(2, 2);

  #pragma unroll 1
  for(int tt=0; tt<NK; ++tt){
    // retire exactly tile tt's loads; keep later tiles in flight across the barrier
    if(tt < NK-2)      { asm volatile("s_waitcnt vmcnt(6)" ::: "memory"); }
    else if(tt == NK-2){ asm volatile("s_waitcnt vmcnt(3)" ::: "memory"); }
    else               { asm volatile("s_waitcnt vmcnt(0)" ::: "memory"); }
    asm volatile("s_barrier" ::: "memory");
    // stage tile tt+3 into buf (tt+3)&3 = buf (tt-1)&3: WAR-safe (all waves
    // finished reading it before the barrier of iter tt).
    if(tt+3 < NK){ GSTAGE(tt+3, (tt+3)&3); }
    const u16* As_ = As[tt&3];
    const u16* Bs_ = Bs[tt&3];
    bf16x8 af[4], bfr[4];
    #pragma unroll
    for(int i=0;i<4;i++){
      int ra = wm*64 + i*16 + c;
      int qa = ((ra&1)*4 + g) ^ ((ra>>1)&7);
      af[i]  = *(const bf16x8*)(&As_[(ra>>1)*64 + qa*8]);
      int rb = wn*64 + i*16 + c;
      int qb = ((rb&1)*4 + g) ^ ((rb>>1)&7);
      bfr[i] = *(const bf16x8*)(&Bs_[(rb>>1)*64 + qb*8]);
    }
    #pragma unroll
    for(int mi=0;mi<4;mi++)
      #pragma unroll
      for(int ni=0;ni<4;ni++)
        acc[mi][ni] = __builtin_amdgcn_mfma_f32_16x16x32_bf16(af[mi], bfr[ni], acc[mi][ni], 0,0,0);
  }
#undef GSTAGE

  if(MODE==1){
    #pragma unroll
    for(int mi=0;mi<4;mi++){
      int mrow = m0 + wm*64 + mi*16 + g*4;
      #pragma unroll
      for(int ni=0;ni<4;ni++){
        int ncol = n0 + wn*64 + ni*16 + c;
        #pragma unroll
        for(int r=0;r<4;r++)
          outf[(size_t)(mrow+r)*N + ncol] = acc[mi][ni][r];
      }
    }
  } else {
    #pragma unroll
    for(int ni=0;ni<4;ni++){
      int n = n0 + wn*64 + ni*16 + c;
      int sel = n>>10, head = (n>>6)&15, d = n&63;
      #pragma unroll
      for(int mi=0;mi<4;mi++){
        int m = m0 + wm*64 + mi*16 + g*4;
        int b = m>>11, l = m&(SEQ-1);
        if(sel<2){
          u16* dst = (sel==0?Qb:Kb) + ((size_t)((b*NHEADS+head)*SEQ + l))*DHEAD + d;
          #pragma unroll
          for(int r=0;r<4;r++) dst[(size_t)r*DHEAD] = f2bf(acc[mi][ni][r]);
        } else {
          ushort4 pk;
          pk.x=f2bf(acc[mi][ni][0]); pk.y=f2bf(acc[mi][ni][1]);
          pk.z=f2bf(acc[mi][ni][2]); pk.w=f2bf(acc[mi][ni][3]);
          *(ushort4*)(&Vtb[((size_t)((b*NHEADS+head)*DHEAD + d))*SEQ + l]) = pk;
        }
      }
    }
  }
}

// ---------------- RoPE: one thread per (l,j), sincos once, loop over bh ----------------
// Q additionally pre-scaled by scale*log2(e) so attn's softmax is a bare exp2.
#define SC2 0.180336879f   // 0.125 * log2(e)
__global__ __launch_bounds__(256) void rope_kernel(u16* __restrict__ Q, u16* __restrict__ Kb){
  int tid = blockIdx.x*256 + threadIdx.x;   // SEQ*32 threads
  int j = tid&31, l = tid>>5;
  float inv = exp2f(-(float)j * (13.28771237954945f/32.0f)); // 10000^(-j/32)
  float sn, cs;
  sincosf((float)l*inv, &sn, &cs);
  size_t base = (size_t)l*DHEAD + 2*j;
  #pragma unroll 4
  for(int bh=0; bh<BHTOT; bh++){
    size_t off = base + (size_t)bh*SEQ*DHEAD;
    ushort2 q2 = *(ushort2*)(&Q[off]);
    float x1=bf2f(q2.x), x2=bf2f(q2.y);
    ushort2 o;
    o.x = f2bf((x1*cs - x2*sn)*SC2); o.y = f2bf((x1*sn + x2*cs)*SC2);
    *(ushort2*)(&Q[off]) = o;
    ushort2 k2 = *(ushort2*)(&Kb[off]);
    x1=bf2f(k2.x); x2=bf2f(k2.y);
    o.x = f2bf(x1*cs - x2*sn); o.y = f2bf(x1*sn + x2*cs);
    *(ushort2*)(&Kb[off]) = o;
  }
}

// ---------------- Flash attention: 8-wave LDS-shared K/V, 4-deep counted-vmcnt pipeline ----------------
// (r10 winner, untouched.) Block = 512 threads (8 waves), grid 64 bh x 4 y.
// Wave w owns strips sA = 8y+w, sB = 63-8y-w -> 65 tiles/wave, uniform.
// 4-deep circular LDS K/V with counted vmcnt; raw v_exp_f32 softmax; in-register
// P via cvt_pk + permlane32_swap (T12); row-sum in VALU.

#define QKS32(QF) { \
  f32x16 z_ = {}; \
  z_ = __builtin_amdgcn_mfma_f32_32x32x16_bf16(kf[0], QF[0], z_, 0,0,0); \
  z_ = __builtin_amdgcn_mfma_f32_32x32x16_bf16(kf[1], QF[1], z_, 0,0,0); \
  z_ = __builtin_amdgcn_mfma_f32_32x32x16_bf16(kf[2], QF[2], z_, 0,0,0); \
  z_ = __builtin_amdgcn_mfma_f32_32x32x16_bf16(kf[3], QF[3], z_, 0,0,0); \
  sc = z_; }

#define LDK { \
  _Pragma("unroll") for(int dk_=0;dk_<4;dk_++){ \
    int kb_ = (c32*128 + dk_*32 + hl*16) ^ ((c32&7)<<4); \
    kf[dk_] = *(const bf16x8*)((const char*)(&Kls[cur][0]) + kb_); } }

#define LDV { \
  _Pragma("unroll") for(int dt_=0;dt_<2;dt_++) \
    _Pragma("unroll") for(int ks_=0;ks_<2;ks_++){ \
      int d_ = dt_*32 + c32; \
      int vb_ = (d_*64 + ks_*32 + hl*16) ^ (((d_>>1)&7)<<4); \
      vf[dt_][ks_] = *(const bf16x8*)((const char*)(&Vls[cur][0]) + vb_); } }

#define EXPPACK(MASKED, LROW) { \
  unsigned int pk_[8]; \
  _Pragma("unroll") for(int j_=0;j_<8;j_++){ \
    float a_ = fexp2(sc[2*j_]); \
    float b_ = fexp2(sc[2*j_+1]); \
    if(MASKED){ \
      int k0_ = ((2*j_)&3)   + 8*((2*j_)>>2)   + 4*hl; \
      int k1_ = ((2*j_+1)&3) + 8*((2*j_+1)>>2) + 4*hl; \
      a_ = (k0_ <= c32) ? a_ : 0.f; \
      b_ = (k1_ <= c32) ? b_ : 0.f; } \
    LROW += a_ + b_; \
    asm("v_cvt_pk_bf16_f32 %0, %1, %2" : "=v"(pk_[j_]) : "v"(a_), "v"(b_)); } \
  plswap(pk_[0], pk_[2]); \
  plswap(pk_[1], pk_[3]); \
  plswap(pk_[4], pk_[6]); \
  plswap(pk_[5], pk_[7]); \
  u32x4 wa_ = { pk_[0], pk_[1], pk_[2], pk_[3] }; \
  u32x4 wb_ = { pk_[4], pk_[5], pk_[6], pk_[7] }; \
  pa0 = __builtin_bit_cast(bf16x8, wa_); \
  pa1 = __builtin_bit_cast(bf16x8, wb_); }

#define PVM32(O0, O1) { \
  O0 = __builtin_amdgcn_mfma_f32_32x32x16_bf16(pa0, vf[0][0], O0, 0,0,0); \
  O0 = __builtin_amdgcn_mfma_f32_32x32x16_bf16(pa1, vf[0][1], O0, 0,0,0); \
  O1 = __builtin_amdgcn_mfma_f32_32x32x16_bf16(pa0, vf[1][0], O1, 0,0,0); \
  O1 = __builtin_amdgcn_mfma_f32_32x32x16_bf16(pa1, vf[1][1], O1, 0,0,0); }

#define STAGE(TILE, BUF) { \
  u16* dst_ = isK ? &Kls[BUF][cch*8] : &Vls[BUF][cch*8]; \
  async_cp16(sbase + soff0 + (size_t)(TILE)*sstep, dst_); }

__global__ __launch_bounds__(512, 2) void attn_kernel(const u16* __restrict__ Q, const u16* __restrict__ Kb,
    const u16* __restrict__ Vt, u16* __restrict__ O){
  __shared__ u16 Kls[4][2048];   // K tile [32 rows][64 d], swizzle-stored, 4-deep
  __shared__ u16 Vls[4][2048];   // Vt tile [64 d][32 l], swizzle-stored, 4-deep
  __shared__ float LsA[8][32];   // per-wave row sums, strip A
  __shared__ float LsB[8][32];   // per-wave row sums, strip B
  int t = threadIdx.x, lane = t&63, w = t>>6;
  int c32 = lane&31, hl = lane>>5, h8 = hl*8;
  int bh = blockIdx.x;
  int b = bh>>4, hh = bh&15;
  int y = blockIdx.y;            // 0..3; y=0 dispatched first = longest (NT=64)
  int sA = 8*y + w;              // 0..31
  int sB = 63 - 8*y - w;         // 32..63  (per-wave work = 65 tiles, uniform)
  int NT = 64 - 8*y;             // block stages tiles 0..NT-1 (NT >= 40 > depth)
  const u16* Qp = Q  + (size_t)bh*SEQ*DHEAD;
  const u16* Kp = Kb + (size_t)bh*SEQ*DHEAD;
  const u16* Vp = Vt + (size_t)bh*DHEAD*SEQ;

  // ---- staging role: waves 0-3 stage K (chunks 0..255), waves 4-7 stage V ----
  bool isK = (w < 4);
  int cch = isK ? t : (t - 256);   // 0..255
  int prow = cch>>3;
  int jsrc = (cch&7) ^ (prow&7);
  size_t soff0, sstep;
  if(isK){
    soff0 = (size_t)prow*64 + (size_t)jsrc*8;
    sstep = 32*64;
  } else {
    int c2 = prow*8 + jsrc;
    soff0 = (size_t)(c2>>2)*SEQ + (size_t)(c2&3)*8;
    sstep = 32;
  }
  const u16* sbase = isK ? Kp : Vp;

  // Q as B-frags for both strips: lane holds Q[wrow + c32][dk*16 + h8 .. +7]
  bf16x8 qfA[4], qfB[4];
  #pragma unroll
  for(int dk=0;dk<4;dk++){
    qfA[dk] = *(const bf16x8*)(&Qp[(size_t)(sA*32 + c32)*DHEAD + dk*16 + h8]);
    qfB[dk] = *(const bf16x8*)(&Qp[(size_t)(sB*32 + c32)*DHEAD + dk*16 + h8]);
  }

  f32x16 oaccA0 = {}, oaccA1 = {}, oaccB0 = {}, oaccB1 = {};
  float lrowA = 0.f, lrowB = 0.f;
  f32x16 sc;
  bf16x8 kf[4], vf[2][2], pa0, pa1;

  // prologue: stage tiles 0..2 into bufs 0..2 (1 load/thread/tile)
  STAGE(0, 0);
  STAGE(1, 1);
  STAGE(2, 2);

  #pragma unroll 1
  for(int tt=0; tt<NT; ++tt){
    // complete the oldest load (tile tt); keep 2 tiles in flight across the barrier
    asm volatile("s_waitcnt vmcnt(2)" ::: "memory");
    asm volatile("s_barrier" ::: "memory");
    // stage tile tt+3 into buf (tt+3)&3 = buf (tt-1)&3: WAR-safe (all waves past
    // compute(tt-1) at the barrier above; DMA write lands after issue).
    if(tt+3 < NT){ STAGE(tt+3, (tt+3)&3); }
    int cur = tt&3;
    if(tt <= sB){
      LDK; LDV;
      QKS32(qfB);
      if(tt == sB){ EXPPACK(1, lrowB); } else { EXPPACK(0, lrowB); }
      PVM32(oaccB0, oaccB1);
      if(tt <= sA){
        QKS32(qfA);
        if(tt == sA){ EXPPACK(1, lrowA); } else { EXPPACK(0, lrowA); }
        PVM32(oaccA0, oaccA1);
      }
    }
  }

  // ---- epilogue: combine k-half sums, broadcast via tiny LDS, write both strips ----
  float lrA = lrowA + __shfl_xor(lrowA, 32);
  float lrB = lrowB + __shfl_xor(lrowB, 32);
  __syncthreads();
  if(hl==0){ LsA[w][c32] = lrA; LsB[w][c32] = lrB; }
  __syncthreads();
  #pragma unroll
  for(int r=0;r<16;r++){
    int row = (r&3)+8*(r>>2)+4*hl;
    float livA = 1.0f/LsA[w][row];
    float livB = 1.0f/LsB[w][row];
    size_t oA = ((size_t)(b*SEQ + sA*32 + row))*DMODEL + hh*DHEAD;
    size_t oB = ((size_t)(b*SEQ + sB*32 + row))*DMODEL + hh*DHEAD;
    O[oA + c32]      = f2bf(oaccA0[r]*livA);
    O[oA + 32 + c32] = f2bf(oaccA1[r]*livA);
    O[oB + c32]      = f2bf(oaccB0[r]*livB);
    O[oB + 32 + c32] = f2bf(oaccB1[r]*livB);
  }
}

// ---------------- launch ----------------
extern "C" void kernel_launch(void* const* d_in, const int* in_sizes, int n_in,
                              void* d_out, int out_size, void* d_ws, size_t ws_size,
                              hipStream_t stream){
  const float* x    = (const float*)d_in[0];
  const float* W_in = (const float*)d_in[1];
  const float* W_o  = (const float*)d_in[2];
  u16* ws = (u16*)d_ws;
  const size_t T16 = (size_t)8*1024*1024;  // 8M bf16 elems = 16 MB per tensor
  u16* h   = ws;            // [8192][1024] bf16
  u16* Qb  = ws +   T16;    // [64][2048][64]
  u16* Kb  = ws + 2*T16;    // [64][2048][64]
  u16* Vtb = ws + 3*T16;    // [64][64][2048]  (V transposed)
  u16* Wb  = ws + 4*T16;    // W_in bf16 [3072][1024]
  u16* Wob = Wb + (size_t)3*DMODEL*DMODEL; // W_o bf16 [1024][1024]
  u16* Ob  = h;             // reuse: h dead after gemm1
  float* out = (float*)d_out;

  const int na4 = 3*DMODEL*DMODEL/4;  // W_in float4 count
  const int nb4 = DMODEL*DMODEL/4;
  cast2_kernel<<<dim3((na4+nb4)/256), dim3(256), 0, stream>>>(W_in, Wb, W_o, Wob, na4);
  ln_kernel<<<dim3(MROWS), dim3(256), 0, stream>>>(x, h);
  gemm_bt<0><<<dim3(3*DMODEL/BN, MROWS/BM), dim3(512), 0, stream>>>(
      h, Wb, Qb, Kb, Vtb, nullptr, MROWS, 3*DMODEL, DMODEL);
  rope_kernel<<<dim3(SEQ*32/256), dim3(256), 0, stream>>>(Qb, Kb);
  attn_kernel<<<dim3(BHTOT, 4), dim3(512), 0, stream>>>(Qb, Kb, Vtb, Ob);
  gemm_bt<1><<<dim3(DMODEL/BN, MROWS/BM), dim3(512), 0, stream>>>(
      Ob, Wob, nullptr, nullptr, nullptr, out, MROWS, DMODEL, DMODEL);
}

// Round 12
// 263.990 us; speedup vs baseline: 1.0752x; 1.0752x over previous
//
#include <hip/hip_runtime.h>
#include <cstdint>

typedef unsigned short u16;
typedef short bf16x8 __attribute__((ext_vector_type(8)));
typedef float f32x4 __attribute__((ext_vector_type(4)));
typedef float f32x16 __attribute__((ext_vector_type(16)));
typedef unsigned int u32x2 __attribute__((ext_vector_type(2)));
typedef unsigned int u32x4 __attribute__((ext_vector_type(4)));

#define NB 4
#define SEQ 2048
#define DMODEL 1024
#define NHEADS 16
#define DHEAD 64
#define BHTOT (NB*NHEADS)   // 64
#define MROWS (NB*SEQ)      // 8192

__device__ __forceinline__ float bf2f(u16 u){
  union { unsigned int i; float f; } x; x.i = ((unsigned int)u)<<16; return x.f;
}
__device__ __forceinline__ u16 f2bf(float f){
  union { float f; unsigned int i; } x; x.f = f;
  unsigned int r = x.i + 0x7fffu + ((x.i>>16)&1u);
  return (u16)(r>>16);
}
// raw v_exp_f32 (r10 win: +13 us total vs libm exp2f's denormal-guard sequence)
__device__ __forceinline__ float fexp2(float x){
#if __has_builtin(__builtin_amdgcn_exp2f)
  return __builtin_amdgcn_exp2f(x);
#else
  return exp2f(x);
#endif
}

typedef const __attribute__((address_space(1))) unsigned int* gas_t;
typedef __attribute__((address_space(3))) unsigned int* las_t;
__device__ __forceinline__ void async_cp16(const void* g, void* l){
  __builtin_amdgcn_global_load_lds((gas_t)g, (las_t)l, 16, 0, 0);
}

// permlane32_swap: rows 32-63 of a exchange with rows 0-31 of b
__device__ __forceinline__ void plswap(unsigned int &a, unsigned int &b){
#if __has_builtin(__builtin_amdgcn_permlane32_swap)
  u32x2 r = __builtin_amdgcn_permlane32_swap(a, b, false, false);
  a = r[0]; b = r[1];
#else
  asm("v_permlane32_swap_b32 %0, %1" : "+v"(a), "+v"(b));
#endif
}

// ---------------- fp32 -> bf16 cast for BOTH weights (one launch) ----------------
__global__ __launch_bounds__(256) void cast2_kernel(const float* __restrict__ wa, u16* __restrict__ oa,
    const float* __restrict__ wb, u16* __restrict__ ob, int na4){
  int i = blockIdx.x*256 + threadIdx.x;
  const float* src; u16* dst; int j;
  if(i < na4){ src = wa; dst = oa; j = i; }
  else       { src = wb; dst = ob; j = i - na4; }
  float4 v = ((const float4*)src)[j];
  ushort4 o;
  o.x=f2bf(v.x); o.y=f2bf(v.y); o.z=f2bf(v.z); o.w=f2bf(v.w);
  ((ushort4*)dst)[j] = o;
}

// ---------------- LayerNorm: x fp32 -> h bf16 (f32 stats) ----------------
__global__ __launch_bounds__(256) void ln_kernel(const float* __restrict__ x, u16* __restrict__ h){
  int row = blockIdx.x;
  const float* xr = x + (size_t)row*DMODEL;
  u16* hr = h + (size_t)row*DMODEL;
  int t = threadIdx.x;
  float4 v = ((const float4*)xr)[t];
  float f0=v.x, f1=v.y, f2=v.z, f3=v.w;
  float s = f0+f1+f2+f3;
  float q = f0*f0+f1*f1+f2*f2+f3*f3;
  #pragma unroll
  for(int off=32; off; off>>=1){ s += __shfl_xor(s, off); q += __shfl_xor(q, off); }
  __shared__ float ss[4], sq[4];
  int wv = t>>6, lane = t&63;
  if(lane==0){ ss[wv]=s; sq[wv]=q; }
  __syncthreads();
  s = ss[0]+ss[1]+ss[2]+ss[3];
  q = sq[0]+sq[1]+sq[2]+sq[3];
  float mu  = s * (1.0f/DMODEL);
  float var = q * (1.0f/DMODEL) - mu*mu;
  float rs  = rsqrtf(var + 1e-8f);
  ushort4 o;
  o.x=f2bf((f0-mu)*rs); o.y=f2bf((f1-mu)*rs); o.z=f2bf((f2-mu)*rs); o.w=f2bf((f3-mu)*rs);
  ((ushort4*)hr)[t] = o;
}

// ---------------- GEMM: C[m,n] = sum_k A[m,k]*Bm[n,k], bf16 MFMA ----------------
// r12 bisect: KEEP the 128x256 tile (85 FLOP/staged-byte vs 128^2's 64, against
// the ~56 B/cy/CU L2 ceiling) but REVERT to the r7/r10-proven 2-deep ping-pong +
// __syncthreads loop. r11's 4-deep variant cost 96 KB LDS -> 1 block/CU -> no
// cross-block overlap (MfmaUtil 19.6, VALUBusy 12: latency-bound). 2-deep = 48 KB
// -> 2 blocks/CU resident again. Pair-row XOR swizzle unchanged (conflicts = 0).
#define BM 128
#define BN 256
#define BK 32

template<int MODE>
__global__ __launch_bounds__(512, 2) void gemm_bt(const u16* __restrict__ A, const u16* __restrict__ Bm,
    u16* __restrict__ Qb, u16* __restrict__ Kb, u16* __restrict__ Vtb, float* __restrict__ outf,
    int M, int N, int K){
  __shared__ u16 As[2][BM*BK];   // 2 x 8 KB
  __shared__ u16 Bs[2][BN*BK];   // 2 x 16 KB
  int t = threadIdx.x;
  int lane = t&63, wv = t>>6;
  int c = lane&15, g = lane>>4;
  int wm = wv>>2, wn = wv&3;     // 2 x 4 wave grid; per-wave 64x64 output
  int m0 = blockIdx.y*BM, n0 = blockIdx.x*BN;

  // staging: chunk cc -> pair-row p = cc>>3, slot j = cc&7, jsrc = j ^ (p&7);
  // global elem = (p*2 + (jsrc>>2))*K + (jsrc&3)*8. A: chunk t. B: chunks t, t+512
  // (t+512 differs only by +64 pair-rows; 64%8==0 so same jsrc, offset +128*K).
  int pA = t>>3, jA = t&7; int jsA = jA ^ (pA&7);
  size_t aoff = (size_t)(pA*2 + (jsA>>2))*K + (jsA&3)*8;
  const u16* Abase = A  + (size_t)m0*K;
  const u16* Bbase = Bm + (size_t)n0*K;

#define GSTAGE(TILE, BUF) { \
    size_t k_ = (size_t)(TILE)*BK; \
    async_cp16(Abase + k_ + aoff,                 &As[BUF][t*8]); \
    async_cp16(Bbase + k_ + aoff,                 &Bs[BUF][t*8]); \
    async_cp16(Bbase + k_ + aoff + 128*(size_t)K, &Bs[BUF][(t+512)*8]); }

  f32x4 acc[4][4] = {};
  int NK = K/BK;   // 32

  GSTAGE(0, 0);
  int cur = 0;
  #pragma unroll 1
  for(int tt=0; tt<NK; ++tt){
    __syncthreads();   // drains staging of buf[cur]; orders prev-iter reads of buf[cur^1]
    if(tt+1 < NK){ GSTAGE(tt+1, cur^1); }
    const u16* As_ = As[cur];
    const u16* Bs_ = Bs[cur];
    bf16x8 af[4], bfr[4];
    #pragma unroll
    for(int i=0;i<4;i++){
      int ra = wm*64 + i*16 + c;
      int qa = ((ra&1)*4 + g) ^ ((ra>>1)&7);
      af[i]  = *(const bf16x8*)(&As_[(ra>>1)*64 + qa*8]);
      int rb = wn*64 + i*16 + c;
      int qb = ((rb&1)*4 + g) ^ ((rb>>1)&7);
      bfr[i] = *(const bf16x8*)(&Bs_[(rb>>1)*64 + qb*8]);
    }
    #pragma unroll
    for(int mi=0;mi<4;mi++)
      #pragma unroll
      for(int ni=0;ni<4;ni++)
        acc[mi][ni] = __builtin_amdgcn_mfma_f32_16x16x32_bf16(af[mi], bfr[ni], acc[mi][ni], 0,0,0);
    cur ^= 1;
  }
#undef GSTAGE

  if(MODE==1){
    #pragma unroll
    for(int mi=0;mi<4;mi++){
      int mrow = m0 + wm*64 + mi*16 + g*4;
      #pragma unroll
      for(int ni=0;ni<4;ni++){
        int ncol = n0 + wn*64 + ni*16 + c;
        #pragma unroll
        for(int r=0;r<4;r++)
          outf[(size_t)(mrow+r)*N + ncol] = acc[mi][ni][r];
      }
    }
  } else {
    #pragma unroll
    for(int ni=0;ni<4;ni++){
      int n = n0 + wn*64 + ni*16 + c;
      int sel = n>>10, head = (n>>6)&15, d = n&63;
      #pragma unroll
      for(int mi=0;mi<4;mi++){
        int m = m0 + wm*64 + mi*16 + g*4;
        int b = m>>11, l = m&(SEQ-1);
        if(sel<2){
          u16* dst = (sel==0?Qb:Kb) + ((size_t)((b*NHEADS+head)*SEQ + l))*DHEAD + d;
          #pragma unroll
          for(int r=0;r<4;r++) dst[(size_t)r*DHEAD] = f2bf(acc[mi][ni][r]);
        } else {
          ushort4 pk;
          pk.x=f2bf(acc[mi][ni][0]); pk.y=f2bf(acc[mi][ni][1]);
          pk.z=f2bf(acc[mi][ni][2]); pk.w=f2bf(acc[mi][ni][3]);
          *(ushort4*)(&Vtb[((size_t)((b*NHEADS+head)*DHEAD + d))*SEQ + l]) = pk;
        }
      }
    }
  }
}

// ---------------- RoPE: one thread per (l,j), sincos once, loop over bh ----------------
// Q additionally pre-scaled by scale*log2(e) so attn's softmax is a bare exp2.
#define SC2 0.180336879f   // 0.125 * log2(e)
__global__ __launch_bounds__(256) void rope_kernel(u16* __restrict__ Q, u16* __restrict__ Kb){
  int tid = blockIdx.x*256 + threadIdx.x;   // SEQ*32 threads
  int j = tid&31, l = tid>>5;
  float inv = exp2f(-(float)j * (13.28771237954945f/32.0f)); // 10000^(-j/32)
  float sn, cs;
  sincosf((float)l*inv, &sn, &cs);
  size_t base = (size_t)l*DHEAD + 2*j;
  #pragma unroll 4
  for(int bh=0; bh<BHTOT; bh++){
    size_t off = base + (size_t)bh*SEQ*DHEAD;
    ushort2 q2 = *(ushort2*)(&Q[off]);
    float x1=bf2f(q2.x), x2=bf2f(q2.y);
    ushort2 o;
    o.x = f2bf((x1*cs - x2*sn)*SC2); o.y = f2bf((x1*sn + x2*cs)*SC2);
    *(ushort2*)(&Q[off]) = o;
    ushort2 k2 = *(ushort2*)(&Kb[off]);
    x1=bf2f(k2.x); x2=bf2f(k2.y);
    o.x = f2bf(x1*cs - x2*sn); o.y = f2bf(x1*sn + x2*cs);
    *(ushort2*)(&Kb[off]) = o;
  }
}

// ---------------- Flash attention: 8-wave LDS-shared K/V, 4-deep counted-vmcnt pipeline ----------------
// (r10 winner, untouched.) Block = 512 threads (8 waves), grid 64 bh x 4 y.
// Wave w owns strips sA = 8y+w, sB = 63-8y-w -> 65 tiles/wave, uniform.
// 4-deep circular LDS K/V with counted vmcnt; raw v_exp_f32 softmax; in-register
// P via cvt_pk + permlane32_swap (T12); row-sum in VALU.

#define QKS32(QF) { \
  f32x16 z_ = {}; \
  z_ = __builtin_amdgcn_mfma_f32_32x32x16_bf16(kf[0], QF[0], z_, 0,0,0); \
  z_ = __builtin_amdgcn_mfma_f32_32x32x16_bf16(kf[1], QF[1], z_, 0,0,0); \
  z_ = __builtin_amdgcn_mfma_f32_32x32x16_bf16(kf[2], QF[2], z_, 0,0,0); \
  z_ = __builtin_amdgcn_mfma_f32_32x32x16_bf16(kf[3], QF[3], z_, 0,0,0); \
  sc = z_; }

#define LDK { \
  _Pragma("unroll") for(int dk_=0;dk_<4;dk_++){ \
    int kb_ = (c32*128 + dk_*32 + hl*16) ^ ((c32&7)<<4); \
    kf[dk_] = *(const bf16x8*)((const char*)(&Kls[cur][0]) + kb_); } }

#define LDV { \
  _Pragma("unroll") for(int dt_=0;dt_<2;dt_++) \
    _Pragma("unroll") for(int ks_=0;ks_<2;ks_++){ \
      int d_ = dt_*32 + c32; \
      int vb_ = (d_*64 + ks_*32 + hl*16) ^ (((d_>>1)&7)<<4); \
      vf[dt_][ks_] = *(const bf16x8*)((const char*)(&Vls[cur][0]) + vb_); } }

#define EXPPACK(MASKED, LROW) { \
  unsigned int pk_[8]; \
  _Pragma("unroll") for(int j_=0;j_<8;j_++){ \
    float a_ = fexp2(sc[2*j_]); \
    float b_ = fexp2(sc[2*j_+1]); \
    if(MASKED){ \
      int k0_ = ((2*j_)&3)   + 8*((2*j_)>>2)   + 4*hl; \
      int k1_ = ((2*j_+1)&3) + 8*((2*j_+1)>>2) + 4*hl; \
      a_ = (k0_ <= c32) ? a_ : 0.f; \
      b_ = (k1_ <= c32) ? b_ : 0.f; } \
    LROW += a_ + b_; \
    asm("v_cvt_pk_bf16_f32 %0, %1, %2" : "=v"(pk_[j_]) : "v"(a_), "v"(b_)); } \
  plswap(pk_[0], pk_[2]); \
  plswap(pk_[1], pk_[3]); \
  plswap(pk_[4], pk_[6]); \
  plswap(pk_[5], pk_[7]); \
  u32x4 wa_ = { pk_[0], pk_[1], pk_[2], pk_[3] }; \
  u32x4 wb_ = { pk_[4], pk_[5], pk_[6], pk_[7] }; \
  pa0 = __builtin_bit_cast(bf16x8, wa_); \
  pa1 = __builtin_bit_cast(bf16x8, wb_); }

#define PVM32(O0, O1) { \
  O0 = __builtin_amdgcn_mfma_f32_32x32x16_bf16(pa0, vf[0][0], O0, 0,0,0); \
  O0 = __builtin_amdgcn_mfma_f32_32x32x16_bf16(pa1, vf[0][1], O0, 0,0,0); \
  O1 = __builtin_amdgcn_mfma_f32_32x32x16_bf16(pa0, vf[1][0], O1, 0,0,0); \
  O1 = __builtin_amdgcn_mfma_f32_32x32x16_bf16(pa1, vf[1][1], O1, 0,0,0); }

#define STAGE(TILE, BUF) { \
  u16* dst_ = isK ? &Kls[BUF][cch*8] : &Vls[BUF][cch*8]; \
  async_cp16(sbase + soff0 + (size_t)(TILE)*sstep, dst_); }

__global__ __launch_bounds__(512, 2) void attn_kernel(const u16* __restrict__ Q, const u16* __restrict__ Kb,
    const u16* __restrict__ Vt, u16* __restrict__ O){
  __shared__ u16 Kls[4][2048];   // K tile [32 rows][64 d], swizzle-stored, 4-deep
  __shared__ u16 Vls[4][2048];   // Vt tile [64 d][32 l], swizzle-stored, 4-deep
  __shared__ float LsA[8][32];   // per-wave row sums, strip A
  __shared__ float LsB[8][32];   // per-wave row sums, strip B
  int t = threadIdx.x, lane = t&63, w = t>>6;
  int c32 = lane&31, hl = lane>>5, h8 = hl*8;
  int bh = blockIdx.x;
  int b = bh>>4, hh = bh&15;
  int y = blockIdx.y;            // 0..3; y=0 dispatched first = longest (NT=64)
  int sA = 8*y + w;              // 0..31
  int sB = 63 - 8*y - w;         // 32..63  (per-wave work = 65 tiles, uniform)
  int NT = 64 - 8*y;             // block stages tiles 0..NT-1 (NT >= 40 > depth)
  const u16* Qp = Q  + (size_t)bh*SEQ*DHEAD;
  const u16* Kp = Kb + (size_t)bh*SEQ*DHEAD;
  const u16* Vp = Vt + (size_t)bh*DHEAD*SEQ;

  // ---- staging role: waves 0-3 stage K (chunks 0..255), waves 4-7 stage V ----
  bool isK = (w < 4);
  int cch = isK ? t : (t - 256);   // 0..255
  int prow = cch>>3;
  int jsrc = (cch&7) ^ (prow&7);
  size_t soff0, sstep;
  if(isK){
    soff0 = (size_t)prow*64 + (size_t)jsrc*8;
    sstep = 32*64;
  } else {
    int c2 = prow*8 + jsrc;
    soff0 = (size_t)(c2>>2)*SEQ + (size_t)(c2&3)*8;
    sstep = 32;
  }
  const u16* sbase = isK ? Kp : Vp;

  // Q as B-frags for both strips: lane holds Q[wrow + c32][dk*16 + h8 .. +7]
  bf16x8 qfA[4], qfB[4];
  #pragma unroll
  for(int dk=0;dk<4;dk++){
    qfA[dk] = *(const bf16x8*)(&Qp[(size_t)(sA*32 + c32)*DHEAD + dk*16 + h8]);
    qfB[dk] = *(const bf16x8*)(&Qp[(size_t)(sB*32 + c32)*DHEAD + dk*16 + h8]);
  }

  f32x16 oaccA0 = {}, oaccA1 = {}, oaccB0 = {}, oaccB1 = {};
  float lrowA = 0.f, lrowB = 0.f;
  f32x16 sc;
  bf16x8 kf[4], vf[2][2], pa0, pa1;

  // prologue: stage tiles 0..2 into bufs 0..2 (1 load/thread/tile)
  STAGE(0, 0);
  STAGE(1, 1);
  STAGE(2, 2);

  #pragma unroll 1
  for(int tt=0; tt<NT; ++tt){
    // complete the oldest load (tile tt); keep 2 tiles in flight across the barrier
    asm volatile("s_waitcnt vmcnt(2)" ::: "memory");
    asm volatile("s_barrier" ::: "memory");
    // stage tile tt+3 into buf (tt+3)&3 = buf (tt-1)&3: WAR-safe (all waves past
    // compute(tt-1) at the barrier above; DMA write lands after issue).
    if(tt+3 < NT){ STAGE(tt+3, (tt+3)&3); }
    int cur = tt&3;
    if(tt <= sB){
      LDK; LDV;
      QKS32(qfB);
      if(tt == sB){ EXPPACK(1, lrowB); } else { EXPPACK(0, lrowB); }
      PVM32(oaccB0, oaccB1);
      if(tt <= sA){
        QKS32(qfA);
        if(tt == sA){ EXPPACK(1, lrowA); } else { EXPPACK(0, lrowA); }
        PVM32(oaccA0, oaccA1);
      }
    }
  }

  // ---- epilogue: combine k-half sums, broadcast via tiny LDS, write both strips ----
  float lrA = lrowA + __shfl_xor(lrowA, 32);
  float lrB = lrowB + __shfl_xor(lrowB, 32);
  __syncthreads();
  if(hl==0){ LsA[w][c32] = lrA; LsB[w][c32] = lrB; }
  __syncthreads();
  #pragma unroll
  for(int r=0;r<16;r++){
    int row = (r&3)+8*(r>>2)+4*hl;
    float livA = 1.0f/LsA[w][row];
    float livB = 1.0f/LsB[w][row];
    size_t oA = ((size_t)(b*SEQ + sA*32 + row))*DMODEL + hh*DHEAD;
    size_t oB = ((size_t)(b*SEQ + sB*32 + row))*DMODEL + hh*DHEAD;
    O[oA + c32]      = f2bf(oaccA0[r]*livA);
    O[oA + 32 + c32] = f2bf(oaccA1[r]*livA);
    O[oB + c32]      = f2bf(oaccB0[r]*livB);
    O[oB + 32 + c32] = f2bf(oaccB1[r]*livB);
  }
}

// ---------------- launch ----------------
extern "C" void kernel_launch(void* const* d_in, const int* in_sizes, int n_in,
                              void* d_out, int out_size, void* d_ws, size_t ws_size,
                              hipStream_t stream){
  const float* x    = (const float*)d_in[0];
  const float* W_in = (const float*)d_in[1];
  const float* W_o  = (const float*)d_in[2];
  u16* ws = (u16*)d_ws;
  const size_t T16 = (size_t)8*1024*1024;  // 8M bf16 elems = 16 MB per tensor
  u16* h   = ws;            // [8192][1024] bf16
  u16* Qb  = ws +   T16;    // [64][2048][64]
  u16* Kb  = ws + 2*T16;    // [64][2048][64]
  u16* Vtb = ws + 3*T16;    // [64][64][2048]  (V transposed)
  u16* Wb  = ws + 4*T16;    // W_in bf16 [3072][1024]
  u16* Wob = Wb + (size_t)3*DMODEL*DMODEL; // W_o bf16 [1024][1024]
  u16* Ob  = h;             // reuse: h dead after gemm1
  float* out = (float*)d_out;

  const int na4 = 3*DMODEL*DMODEL/4;  // W_in float4 count
  const int nb4 = DMODEL*DMODEL/4;
  cast2_kernel<<<dim3((na4+nb4)/256), dim3(256), 0, stream>>>(W_in, Wb, W_o, Wob, na4);
  ln_kernel<<<dim3(MROWS), dim3(256), 0, stream>>>(x, h);
  gemm_bt<0><<<dim3(3*DMODEL/BN, MROWS/BM), dim3(512), 0, stream>>>(
      h, Wb, Qb, Kb, Vtb, nullptr, MROWS, 3*DMODEL, DMODEL);
  rope_kernel<<<dim3(SEQ*32/256), dim3(256), 0, stream>>>(Qb, Kb);
  attn_kernel<<<dim3(BHTOT, 4), dim3(512), 0, stream>>>(Qb, Kb, Vtb, Ob);
  gemm_bt<1><<<dim3(DMODEL/BN, MROWS/BM), dim3(512), 0, stream>>>(
      Ob, Wob, nullptr, nullptr, nullptr, out, MROWS, DMODEL, DMODEL);
}

// Round 13
// 251.132 us; speedup vs baseline: 1.1302x; 1.0512x over previous
//
#include <hip/hip_runtime.h>
#include <cstdint>

typedef unsigned short u16;
typedef short bf16x8 __attribute__((ext_vector_type(8)));
typedef float f32x4 __attribute__((ext_vector_type(4)));
typedef float f32x16 __attribute__((ext_vector_type(16)));
typedef unsigned int u32x2 __attribute__((ext_vector_type(2)));
typedef unsigned int u32x4 __attribute__((ext_vector_type(4)));

#define NB 4
#define SEQ 2048
#define DMODEL 1024
#define NHEADS 16
#define DHEAD 64
#define BHTOT (NB*NHEADS)   // 64
#define MROWS (NB*SEQ)      // 8192
#define SC2 0.180336879f    // 0.125 * log2(e)  (Q pre-scale so attn softmax is bare exp2)

__device__ __forceinline__ float bf2f(u16 u){
  union { unsigned int i; float f; } x; x.i = ((unsigned int)u)<<16; return x.f;
}
__device__ __forceinline__ u16 f2bf(float f){
  union { float f; unsigned int i; } x; x.f = f;
  unsigned int r = x.i + 0x7fffu + ((x.i>>16)&1u);
  return (u16)(r>>16);
}
// raw v_exp_f32 (r10 win vs libm exp2f's denormal-guard sequence)
__device__ __forceinline__ float fexp2(float x){
#if __has_builtin(__builtin_amdgcn_exp2f)
  return __builtin_amdgcn_exp2f(x);
#else
  return exp2f(x);
#endif
}

typedef const __attribute__((address_space(1))) unsigned int* gas_t;
typedef __attribute__((address_space(3))) unsigned int* las_t;
__device__ __forceinline__ void async_cp16(const void* g, void* l){
  __builtin_amdgcn_global_load_lds((gas_t)g, (las_t)l, 16, 0, 0);
}

// permlane32_swap: rows 32-63 of a exchange with rows 0-31 of b
__device__ __forceinline__ void plswap(unsigned int &a, unsigned int &b){
#if __has_builtin(__builtin_amdgcn_permlane32_swap)
  u32x2 r = __builtin_amdgcn_permlane32_swap(a, b, false, false);
  a = r[0]; b = r[1];
#else
  asm("v_permlane32_swap_b32 %0, %1" : "+v"(a), "+v"(b));
#endif
}

// ---------------- cast weights to bf16 + build RoPE cos/sin table (one launch) ----------------
// Third index range computes Tab[l*32+j] = (cos, sin)(l * 10000^(-j/32)) — consumed
// by gemm0's fused-RoPE epilogue (r13: rope_kernel eliminated).
__global__ __launch_bounds__(256) void cast2_kernel(const float* __restrict__ wa, u16* __restrict__ oa,
    const float* __restrict__ wb, u16* __restrict__ ob, int na4, int nb4, float2* __restrict__ tab){
  int i = blockIdx.x*256 + threadIdx.x;
  if(i < na4){
    float4 v = ((const float4*)wa)[i];
    ushort4 o;
    o.x=f2bf(v.x); o.y=f2bf(v.y); o.z=f2bf(v.z); o.w=f2bf(v.w);
    ((ushort4*)oa)[i] = o;
  } else if(i < na4+nb4){
    int j = i - na4;
    float4 v = ((const float4*)wb)[j];
    ushort4 o;
    o.x=f2bf(v.x); o.y=f2bf(v.y); o.z=f2bf(v.z); o.w=f2bf(v.w);
    ((ushort4*)ob)[j] = o;
  } else {
    int idx = i - na4 - nb4;        // 0 .. SEQ*32-1
    if(idx < SEQ*32){
      int j = idx & 31, l = idx >> 5;
      float inv = exp2f(-(float)j * (13.28771237954945f/32.0f)); // 10000^(-j/32)
      float sn, cs;
      sincosf((float)l*inv, &sn, &cs);
      tab[idx] = make_float2(cs, sn);
    }
  }
}

// ---------------- LayerNorm: x fp32 -> h bf16 (f32 stats) ----------------
__global__ __launch_bounds__(256) void ln_kernel(const float* __restrict__ x, u16* __restrict__ h){
  int row = blockIdx.x;
  const float* xr = x + (size_t)row*DMODEL;
  u16* hr = h + (size_t)row*DMODEL;
  int t = threadIdx.x;
  float4 v = ((const float4*)xr)[t];
  float f0=v.x, f1=v.y, f2=v.z, f3=v.w;
  float s = f0+f1+f2+f3;
  float q = f0*f0+f1*f1+f2*f2+f3*f3;
  #pragma unroll
  for(int off=32; off; off>>=1){ s += __shfl_xor(s, off); q += __shfl_xor(q, off); }
  __shared__ float ss[4], sq[4];
  int wv = t>>6, lane = t&63;
  if(lane==0){ ss[wv]=s; sq[wv]=q; }
  __syncthreads();
  s = ss[0]+ss[1]+ss[2]+ss[3];
  q = sq[0]+sq[1]+sq[2]+sq[3];
  float mu  = s * (1.0f/DMODEL);
  float var = q * (1.0f/DMODEL) - mu*mu;
  float rs  = rsqrtf(var + 1e-8f);
  ushort4 o;
  o.x=f2bf((f0-mu)*rs); o.y=f2bf((f1-mu)*rs); o.z=f2bf((f2-mu)*rs); o.w=f2bf((f3-mu)*rs);
  ((ushort4*)hr)[t] = o;
}

// ---------------- GEMM: C[m,n] = sum_k A[m,k]*Bm[n,k], bf16 MFMA ----------------
// r13: exact r10 winner (128x128, 256 thr, 2-deep ping-pong + pair-row XOR swizzle;
// 73 us, conflicts 0) + fused RoPE in the MODE0 Q/K epilogue:
//   partner value C[l][d^1] via __shfl_xor(v,1) (d parity == lane parity; sel/head
//   are wave-uniform so the shuffle is branch-safe), cos/sin from Tab[l][d>>1].
//   Q additionally scaled by SC2. Rotation in fp32 before the single bf16 round
//   (previously: bf16 write -> rope read/rotate/re-write = extra 64MB round-trip).
#define BM 128
#define BN 128
#define BK 32

template<int MODE>
__global__ __launch_bounds__(256) void gemm_bt(const u16* __restrict__ A, const u16* __restrict__ Bm,
    u16* __restrict__ Qb, u16* __restrict__ Kb, u16* __restrict__ Vtb, float* __restrict__ outf,
    const float2* __restrict__ Tab, int M, int N, int K){
  __shared__ u16 As[2][BM*BK];
  __shared__ u16 Bs[2][BN*BK];
  int t = threadIdx.x;
  int lane = t&63, wv = t>>6;
  int c = lane&15, g = lane>>4;
  int wm = wv>>1, wn = wv&1;
  int m0 = blockIdx.y*BM, n0 = blockIdx.x*BN;

  int p0 = t>>3,        j0 = t&7;        int js0 = j0 ^ (p0&7);
  int p1 = (t+256)>>3,  j1 = t&7;        int js1 = j1 ^ (p1&7);
  size_t aoff0 = (size_t)(p0*2 + (js0>>2))*K + (js0&3)*8;
  size_t aoff1 = (size_t)(p1*2 + (js1>>2))*K + (js1&3)*8;
  const u16* Abase = A  + (size_t)m0*K;
  const u16* Bbase = Bm + (size_t)n0*K;

  f32x4 acc[4][4] = {};

  async_cp16(Abase + aoff0, &As[0][t*8]);
  async_cp16(Abase + aoff1, &As[0][(t+256)*8]);
  async_cp16(Bbase + aoff0, &Bs[0][t*8]);
  async_cp16(Bbase + aoff1, &Bs[0][(t+256)*8]);

  int cur = 0;
  for(int k0=0;k0<K;k0+=BK){
    __syncthreads();
    if(k0+BK < K){
      int nb = cur^1;
      async_cp16(Abase + (k0+BK) + aoff0, &As[nb][t*8]);
      async_cp16(Abase + (k0+BK) + aoff1, &As[nb][(t+256)*8]);
      async_cp16(Bbase + (k0+BK) + aoff0, &Bs[nb][t*8]);
      async_cp16(Bbase + (k0+BK) + aoff1, &Bs[nb][(t+256)*8]);
    }
    bf16x8 af[4], bfr[4];
    #pragma unroll
    for(int i=0;i<4;i++){
      int ra = wm*64 + i*16 + c;
      int qa = ((ra&1)*4 + g) ^ ((ra>>1)&7);
      af[i]  = *(const bf16x8*)(&As[cur][(ra>>1)*64 + qa*8]);
      int rb = wn*64 + i*16 + c;
      int qb = ((rb&1)*4 + g) ^ ((rb>>1)&7);
      bfr[i] = *(const bf16x8*)(&Bs[cur][(rb>>1)*64 + qb*8]);
    }
    #pragma unroll
    for(int mi=0;mi<4;mi++)
      #pragma unroll
      for(int ni=0;ni<4;ni++)
        acc[mi][ni] = __builtin_amdgcn_mfma_f32_16x16x32_bf16(af[mi], bfr[ni], acc[mi][ni], 0,0,0);
    cur ^= 1;
  }
  if(MODE==1){
    #pragma unroll
    for(int mi=0;mi<4;mi++){
      int mrow = m0 + wm*64 + mi*16 + g*4;
      #pragma unroll
      for(int ni=0;ni<4;ni++){
        int ncol = n0 + wn*64 + ni*16 + c;
        #pragma unroll
        for(int r=0;r<4;r++)
          outf[(size_t)(mrow+r)*N + ncol] = acc[mi][ni][r];
      }
    }
  } else {
    #pragma unroll
    for(int ni=0;ni<4;ni++){
      int n = n0 + wn*64 + ni*16 + c;
      int sel = n>>10, head = (n>>6)&15, d = n&63;
      int jj = d>>1;
      float sgn = (d&1) ? 1.0f : -1.0f;
      float qs  = (sel==0) ? SC2 : 1.0f;
      #pragma unroll
      for(int mi=0;mi<4;mi++){
        int m = m0 + wm*64 + mi*16 + g*4;
        int b = m>>11, l = m&(SEQ-1);
        if(sel<2){
          // fused RoPE: v = C[l+r][d], partner p = C[l+r][d^1] from lane^1.
          // even d: v*cs - p*sn ; odd d: v*cs + p*sn  (then Q x SC2)
          u16* dst = (sel==0?Qb:Kb) + ((size_t)((b*NHEADS+head)*SEQ + l))*DHEAD + d;
          #pragma unroll
          for(int r=0;r<4;r++){
            float v = acc[mi][ni][r];
            float p = __shfl_xor(v, 1);
            float2 t2 = Tab[(size_t)(l+r)*32 + jj];
            float o = (v*t2.x + sgn*(p*t2.y)) * qs;
            dst[(size_t)r*DHEAD] = f2bf(o);
          }
        } else {
          ushort4 pk;
          pk.x=f2bf(acc[mi][ni][0]); pk.y=f2bf(acc[mi][ni][1]);
          pk.z=f2bf(acc[mi][ni][2]); pk.w=f2bf(acc[mi][ni][3]);
          *(ushort4*)(&Vtb[((size_t)((b*NHEADS+head)*DHEAD + d))*SEQ + l]) = pk;
        }
      }
    }
  }
}

// ---------------- Flash attention: 8-wave LDS-shared K/V, 4-deep counted-vmcnt pipeline ----------------
// (r10 winner, untouched.) Block = 512 threads (8 waves), grid 64 bh x 4 y.
// Wave w owns strips sA = 8y+w, sB = 63-8y-w -> 65 tiles/wave, uniform.
// 4-deep circular LDS K/V with counted vmcnt; raw v_exp_f32 softmax; in-register
// P via cvt_pk + permlane32_swap (T12); row-sum in VALU.

#define QKS32(QF) { \
  f32x16 z_ = {}; \
  z_ = __builtin_amdgcn_mfma_f32_32x32x16_bf16(kf[0], QF[0], z_, 0,0,0); \
  z_ = __builtin_amdgcn_mfma_f32_32x32x16_bf16(kf[1], QF[1], z_, 0,0,0); \
  z_ = __builtin_amdgcn_mfma_f32_32x32x16_bf16(kf[2], QF[2], z_, 0,0,0); \
  z_ = __builtin_amdgcn_mfma_f32_32x32x16_bf16(kf[3], QF[3], z_, 0,0,0); \
  sc = z_; }

#define LDK { \
  _Pragma("unroll") for(int dk_=0;dk_<4;dk_++){ \
    int kb_ = (c32*128 + dk_*32 + hl*16) ^ ((c32&7)<<4); \
    kf[dk_] = *(const bf16x8*)((const char*)(&Kls[cur][0]) + kb_); } }

#define LDV { \
  _Pragma("unroll") for(int dt_=0;dt_<2;dt_++) \
    _Pragma("unroll") for(int ks_=0;ks_<2;ks_++){ \
      int d_ = dt_*32 + c32; \
      int vb_ = (d_*64 + ks_*32 + hl*16) ^ (((d_>>1)&7)<<4); \
      vf[dt_][ks_] = *(const bf16x8*)((const char*)(&Vls[cur][0]) + vb_); } }

#define EXPPACK(MASKED, LROW) { \
  unsigned int pk_[8]; \
  _Pragma("unroll") for(int j_=0;j_<8;j_++){ \
    float a_ = fexp2(sc[2*j_]); \
    float b_ = fexp2(sc[2*j_+1]); \
    if(MASKED){ \
      int k0_ = ((2*j_)&3)   + 8*((2*j_)>>2)   + 4*hl; \
      int k1_ = ((2*j_+1)&3) + 8*((2*j_+1)>>2) + 4*hl; \
      a_ = (k0_ <= c32) ? a_ : 0.f; \
      b_ = (k1_ <= c32) ? b_ : 0.f; } \
    LROW += a_ + b_; \
    asm("v_cvt_pk_bf16_f32 %0, %1, %2" : "=v"(pk_[j_]) : "v"(a_), "v"(b_)); } \
  plswap(pk_[0], pk_[2]); \
  plswap(pk_[1], pk_[3]); \
  plswap(pk_[4], pk_[6]); \
  plswap(pk_[5], pk_[7]); \
  u32x4 wa_ = { pk_[0], pk_[1], pk_[2], pk_[3] }; \
  u32x4 wb_ = { pk_[4], pk_[5], pk_[6], pk_[7] }; \
  pa0 = __builtin_bit_cast(bf16x8, wa_); \
  pa1 = __builtin_bit_cast(bf16x8, wb_); }

#define PVM32(O0, O1) { \
  O0 = __builtin_amdgcn_mfma_f32_32x32x16_bf16(pa0, vf[0][0], O0, 0,0,0); \
  O0 = __builtin_amdgcn_mfma_f32_32x32x16_bf16(pa1, vf[0][1], O0, 0,0,0); \
  O1 = __builtin_amdgcn_mfma_f32_32x32x16_bf16(pa0, vf[1][0], O1, 0,0,0); \
  O1 = __builtin_amdgcn_mfma_f32_32x32x16_bf16(pa1, vf[1][1], O1, 0,0,0); }

#define STAGE(TILE, BUF) { \
  u16* dst_ = isK ? &Kls[BUF][cch*8] : &Vls[BUF][cch*8]; \
  async_cp16(sbase + soff0 + (size_t)(TILE)*sstep, dst_); }

__global__ __launch_bounds__(512, 2) void attn_kernel(const u16* __restrict__ Q, const u16* __restrict__ Kb,
    const u16* __restrict__ Vt, u16* __restrict__ O){
  __shared__ u16 Kls[4][2048];   // K tile [32 rows][64 d], swizzle-stored, 4-deep
  __shared__ u16 Vls[4][2048];   // Vt tile [64 d][32 l], swizzle-stored, 4-deep
  __shared__ float LsA[8][32];   // per-wave row sums, strip A
  __shared__ float LsB[8][32];   // per-wave row sums, strip B
  int t = threadIdx.x, lane = t&63, w = t>>6;
  int c32 = lane&31, hl = lane>>5, h8 = hl*8;
  int bh = blockIdx.x;
  int b = bh>>4, hh = bh&15;
  int y = blockIdx.y;            // 0..3; y=0 dispatched first = longest (NT=64)
  int sA = 8*y + w;              // 0..31
  int sB = 63 - 8*y - w;         // 32..63  (per-wave work = 65 tiles, uniform)
  int NT = 64 - 8*y;             // block stages tiles 0..NT-1 (NT >= 40 > depth)
  const u16* Qp = Q  + (size_t)bh*SEQ*DHEAD;
  const u16* Kp = Kb + (size_t)bh*SEQ*DHEAD;
  const u16* Vp = Vt + (size_t)bh*DHEAD*SEQ;

  // ---- staging role: waves 0-3 stage K (chunks 0..255), waves 4-7 stage V ----
  bool isK = (w < 4);
  int cch = isK ? t : (t - 256);   // 0..255
  int prow = cch>>3;
  int jsrc = (cch&7) ^ (prow&7);
  size_t soff0, sstep;
  if(isK){
    soff0 = (size_t)prow*64 + (size_t)jsrc*8;
    sstep = 32*64;
  } else {
    int c2 = prow*8 + jsrc;
    soff0 = (size_t)(c2>>2)*SEQ + (size_t)(c2&3)*8;
    sstep = 32;
  }
  const u16* sbase = isK ? Kp : Vp;

  // Q as B-frags for both strips: lane holds Q[wrow + c32][dk*16 + h8 .. +7]
  bf16x8 qfA[4], qfB[4];
  #pragma unroll
  for(int dk=0;dk<4;dk++){
    qfA[dk] = *(const bf16x8*)(&Qp[(size_t)(sA*32 + c32)*DHEAD + dk*16 + h8]);
    qfB[dk] = *(const bf16x8*)(&Qp[(size_t)(sB*32 + c32)*DHEAD + dk*16 + h8]);
  }

  f32x16 oaccA0 = {}, oaccA1 = {}, oaccB0 = {}, oaccB1 = {};
  float lrowA = 0.f, lrowB = 0.f;
  f32x16 sc;
  bf16x8 kf[4], vf[2][2], pa0, pa1;

  // prologue: stage tiles 0..2 into bufs 0..2 (1 load/thread/tile)
  STAGE(0, 0);
  STAGE(1, 1);
  STAGE(2, 2);

  #pragma unroll 1
  for(int tt=0; tt<NT; ++tt){
    // complete the oldest load (tile tt); keep 2 tiles in flight across the barrier
    asm volatile("s_waitcnt vmcnt(2)" ::: "memory");
    asm volatile("s_barrier" ::: "memory");
    // stage tile tt+3 into buf (tt+3)&3 = buf (tt-1)&3: WAR-safe (all waves past
    // compute(tt-1) at the barrier above; DMA write lands after issue).
    if(tt+3 < NT){ STAGE(tt+3, (tt+3)&3); }
    int cur = tt&3;
    if(tt <= sB){
      LDK; LDV;
      QKS32(qfB);
      if(tt == sB){ EXPPACK(1, lrowB); } else { EXPPACK(0, lrowB); }
      PVM32(oaccB0, oaccB1);
      if(tt <= sA){
        QKS32(qfA);
        if(tt == sA){ EXPPACK(1, lrowA); } else { EXPPACK(0, lrowA); }
        PVM32(oaccA0, oaccA1);
      }
    }
  }

  // ---- epilogue: combine k-half sums, broadcast via tiny LDS, write both strips ----
  float lrA = lrowA + __shfl_xor(lrowA, 32);
  float lrB = lrowB + __shfl_xor(lrowB, 32);
  __syncthreads();
  if(hl==0){ LsA[w][c32] = lrA; LsB[w][c32] = lrB; }
  __syncthreads();
  #pragma unroll
  for(int r=0;r<16;r++){
    int row = (r&3)+8*(r>>2)+4*hl;
    float livA = 1.0f/LsA[w][row];
    float livB = 1.0f/LsB[w][row];
    size_t oA = ((size_t)(b*SEQ + sA*32 + row))*DMODEL + hh*DHEAD;
    size_t oB = ((size_t)(b*SEQ + sB*32 + row))*DMODEL + hh*DHEAD;
    O[oA + c32]      = f2bf(oaccA0[r]*livA);
    O[oA + 32 + c32] = f2bf(oaccA1[r]*livA);
    O[oB + c32]      = f2bf(oaccB0[r]*livB);
    O[oB + 32 + c32] = f2bf(oaccB1[r]*livB);
  }
}

// ---------------- launch ----------------
extern "C" void kernel_launch(void* const* d_in, const int* in_sizes, int n_in,
                              void* d_out, int out_size, void* d_ws, size_t ws_size,
                              hipStream_t stream){
  const float* x    = (const float*)d_in[0];
  const float* W_in = (const float*)d_in[1];
  const float* W_o  = (const float*)d_in[2];
  u16* ws = (u16*)d_ws;
  const size_t T16 = (size_t)8*1024*1024;  // 8M bf16 elems = 16 MB per tensor
  u16* h   = ws;            // [8192][1024] bf16
  u16* Qb  = ws +   T16;    // [64][2048][64]
  u16* Kb  = ws + 2*T16;    // [64][2048][64]
  u16* Vtb = ws + 3*T16;    // [64][64][2048]  (V transposed)
  u16* Wb  = ws + 4*T16;    // W_in bf16 [3072][1024]
  u16* Wob = Wb + (size_t)3*DMODEL*DMODEL; // W_o bf16 [1024][1024]
  float2* Tab = (float2*)(Wob + (size_t)DMODEL*DMODEL); // RoPE table [SEQ][32] (cos,sin)
  u16* Ob  = h;             // reuse: h dead after gemm1
  float* out = (float*)d_out;

  const int na4 = 3*DMODEL*DMODEL/4;  // W_in float4 count
  const int nb4 = DMODEL*DMODEL/4;
  const int ncast = na4 + nb4 + SEQ*32;
  cast2_kernel<<<dim3((ncast+255)/256), dim3(256), 0, stream>>>(W_in, Wb, W_o, Wob, na4, nb4, Tab);
  ln_kernel<<<dim3(MROWS), dim3(256), 0, stream>>>(x, h);
  gemm_bt<0><<<dim3(3*DMODEL/BN, MROWS/BM), dim3(256), 0, stream>>>(
      h, Wb, Qb, Kb, Vtb, nullptr, (const float2*)Tab, MROWS, 3*DMODEL, DMODEL);
  attn_kernel<<<dim3(BHTOT, 4), dim3(512), 0, stream>>>(Qb, Kb, Vtb, Ob);
  gemm_bt<1><<<dim3(DMODEL/BN, MROWS/BM), dim3(256), 0, stream>>>(
      Ob, Wob, nullptr, nullptr, nullptr, out, nullptr, MROWS, DMODEL, DMODEL);
}

// Round 15
// 246.844 us; speedup vs baseline: 1.1499x; 1.0174x over previous
//
#include <hip/hip_runtime.h>
#include <cstdint>

typedef unsigned short u16;
typedef short bf16x8 __attribute__((ext_vector_type(8)));
typedef float f32x4 __attribute__((ext_vector_type(4)));
typedef float f32x16 __attribute__((ext_vector_type(16)));
typedef unsigned int u32x2 __attribute__((ext_vector_type(2)));
typedef unsigned int u32x4 __attribute__((ext_vector_type(4)));

#define NB 4
#define SEQ 2048
#define DMODEL 1024
#define NHEADS 16
#define DHEAD 64
#define BHTOT (NB*NHEADS)   // 64
#define MROWS (NB*SEQ)      // 8192
#define SC2 0.180336879f    // 0.125 * log2(e)  (Q pre-scale so attn softmax is bare exp2)

__device__ __forceinline__ float bf2f(u16 u){
  union { unsigned int i; float f; } x; x.i = ((unsigned int)u)<<16; return x.f;
}
__device__ __forceinline__ u16 f2bf(float f){
  union { float f; unsigned int i; } x; x.f = f;
  unsigned int r = x.i + 0x7fffu + ((x.i>>16)&1u);
  return (u16)(r>>16);
}
// raw v_exp_f32 (r10 win vs libm exp2f's denormal-guard sequence)
__device__ __forceinline__ float fexp2(float x){
#if __has_builtin(__builtin_amdgcn_exp2f)
  return __builtin_amdgcn_exp2f(x);
#else
  return exp2f(x);
#endif
}

typedef const __attribute__((address_space(1))) unsigned int* gas_t;
typedef __attribute__((address_space(3))) unsigned int* las_t;
__device__ __forceinline__ void async_cp16(const void* g, void* l){
  __builtin_amdgcn_global_load_lds((gas_t)g, (las_t)l, 16, 0, 0);
}

// permlane32_swap: rows 32-63 of a exchange with rows 0-31 of b
__device__ __forceinline__ void plswap(unsigned int &a, unsigned int &b){
#if __has_builtin(__builtin_amdgcn_permlane32_swap)
  u32x2 r = __builtin_amdgcn_permlane32_swap(a, b, false, false);
  a = r[0]; b = r[1];
#else
  asm("v_permlane32_swap_b32 %0, %1" : "+v"(a), "+v"(b));
#endif
}

// ---------------- prep: LayerNorm + weight casts + RoPE table in ONE launch ----------------
// r14: merged cast2_kernel + ln_kernel (kernel count 5 -> 4) to probe the
// launch-boundary overhead theory. Bodies are byte-identical to r13's kernels;
// blocks [0, MROWS) do LN rows, the rest do the cast/table index range.
__global__ __launch_bounds__(256) void prep_kernel(const float* __restrict__ x, u16* __restrict__ h,
    const float* __restrict__ wa, u16* __restrict__ oa,
    const float* __restrict__ wb, u16* __restrict__ ob,
    int na4, int nb4, float2* __restrict__ tab){
  int bid = blockIdx.x;
  int t = threadIdx.x;
  if(bid < MROWS){
    // ---- LayerNorm row ----
    const float* xr = x + (size_t)bid*DMODEL;
    u16* hr = h + (size_t)bid*DMODEL;
    float4 v = ((const float4*)xr)[t];
    float f0=v.x, f1=v.y, f2=v.z, f3=v.w;
    float s = f0+f1+f2+f3;
    float q = f0*f0+f1*f1+f2*f2+f3*f3;
    #pragma unroll
    for(int off=32; off; off>>=1){ s += __shfl_xor(s, off); q += __shfl_xor(q, off); }
    __shared__ float ss[4], sq[4];
    int wv = t>>6, lane = t&63;
    if(lane==0){ ss[wv]=s; sq[wv]=q; }
    __syncthreads();
    s = ss[0]+ss[1]+ss[2]+ss[3];
    q = sq[0]+sq[1]+sq[2]+sq[3];
    float mu  = s * (1.0f/DMODEL);
    float var = q * (1.0f/DMODEL) - mu*mu;
    float rs  = rsqrtf(var + 1e-8f);
    ushort4 o;
    o.x=f2bf((f0-mu)*rs); o.y=f2bf((f1-mu)*rs); o.z=f2bf((f2-mu)*rs); o.w=f2bf((f3-mu)*rs);
    ((ushort4*)hr)[t] = o;
  } else {
    // ---- weight cast + RoPE table ----
    int i = (bid - MROWS)*256 + t;
    if(i < na4){
      float4 v = ((const float4*)wa)[i];
      ushort4 o;
      o.x=f2bf(v.x); o.y=f2bf(v.y); o.z=f2bf(v.z); o.w=f2bf(v.w);
      ((ushort4*)oa)[i] = o;
    } else if(i < na4+nb4){
      int j = i - na4;
      float4 v = ((const float4*)wb)[j];
      ushort4 o;
      o.x=f2bf(v.x); o.y=f2bf(v.y); o.z=f2bf(v.z); o.w=f2bf(v.w);
      ((ushort4*)ob)[j] = o;
    } else {
      int idx = i - na4 - nb4;        // 0 .. SEQ*32-1
      if(idx < SEQ*32){
        int j = idx & 31, l = idx >> 5;
        float inv = exp2f(-(float)j * (13.28771237954945f/32.0f)); // 10000^(-j/32)
        float sn, cs;
        sincosf((float)l*inv, &sn, &cs);
        tab[idx] = make_float2(cs, sn);
      }
    }
  }
}

// ---------------- GEMM: C[m,n] = sum_k A[m,k]*Bm[n,k], bf16 MFMA ----------------
// r13 winner, untouched: 128x128, 256 thr, 2-deep ping-pong + pair-row XOR swizzle
// (conflicts 0) + fused RoPE in the MODE0 Q/K epilogue (fp32 rotation before the
// single bf16 round; partner via __shfl_xor(v,1), cos/sin from Tab).
#define BM 128
#define BN 128
#define BK 32

template<int MODE>
__global__ __launch_bounds__(256) void gemm_bt(const u16* __restrict__ A, const u16* __restrict__ Bm,
    u16* __restrict__ Qb, u16* __restrict__ Kb, u16* __restrict__ Vtb, float* __restrict__ outf,
    const float2* __restrict__ Tab, int M, int N, int K){
  __shared__ u16 As[2][BM*BK];
  __shared__ u16 Bs[2][BN*BK];
  int t = threadIdx.x;
  int lane = t&63, wv = t>>6;
  int c = lane&15, g = lane>>4;
  int wm = wv>>1, wn = wv&1;
  int m0 = blockIdx.y*BM, n0 = blockIdx.x*BN;

  int p0 = t>>3,        j0 = t&7;        int js0 = j0 ^ (p0&7);
  int p1 = (t+256)>>3,  j1 = t&7;        int js1 = j1 ^ (p1&7);
  size_t aoff0 = (size_t)(p0*2 + (js0>>2))*K + (js0&3)*8;
  size_t aoff1 = (size_t)(p1*2 + (js1>>2))*K + (js1&3)*8;
  const u16* Abase = A  + (size_t)m0*K;
  const u16* Bbase = Bm + (size_t)n0*K;

  f32x4 acc[4][4] = {};

  async_cp16(Abase + aoff0, &As[0][t*8]);
  async_cp16(Abase + aoff1, &As[0][(t+256)*8]);
  async_cp16(Bbase + aoff0, &Bs[0][t*8]);
  async_cp16(Bbase + aoff1, &Bs[0][(t+256)*8]);

  int cur = 0;
  for(int k0=0;k0<K;k0+=BK){
    __syncthreads();
    if(k0+BK < K){
      int nb = cur^1;
      async_cp16(Abase + (k0+BK) + aoff0, &As[nb][t*8]);
      async_cp16(Abase + (k0+BK) + aoff1, &As[nb][(t+256)*8]);
      async_cp16(Bbase + (k0+BK) + aoff0, &Bs[nb][t*8]);
      async_cp16(Bbase + (k0+BK) + aoff1, &Bs[nb][(t+256)*8]);
    }
    bf16x8 af[4], bfr[4];
    #pragma unroll
    for(int i=0;i<4;i++){
      int ra = wm*64 + i*16 + c;
      int qa = ((ra&1)*4 + g) ^ ((ra>>1)&7);
      af[i]  = *(const bf16x8*)(&As[cur][(ra>>1)*64 + qa*8]);
      int rb = wn*64 + i*16 + c;
      int qb = ((rb&1)*4 + g) ^ ((rb>>1)&7);
      bfr[i] = *(const bf16x8*)(&Bs[cur][(rb>>1)*64 + qb*8]);
    }
    #pragma unroll
    for(int mi=0;mi<4;mi++)
      #pragma unroll
      for(int ni=0;ni<4;ni++)
        acc[mi][ni] = __builtin_amdgcn_mfma_f32_16x16x32_bf16(af[mi], bfr[ni], acc[mi][ni], 0,0,0);
    cur ^= 1;
  }
  if(MODE==1){
    #pragma unroll
    for(int mi=0;mi<4;mi++){
      int mrow = m0 + wm*64 + mi*16 + g*4;
      #pragma unroll
      for(int ni=0;ni<4;ni++){
        int ncol = n0 + wn*64 + ni*16 + c;
        #pragma unroll
        for(int r=0;r<4;r++)
          outf[(size_t)(mrow+r)*N + ncol] = acc[mi][ni][r];
      }
    }
  } else {
    #pragma unroll
    for(int ni=0;ni<4;ni++){
      int n = n0 + wn*64 + ni*16 + c;
      int sel = n>>10, head = (n>>6)&15, d = n&63;
      int jj = d>>1;
      float sgn = (d&1) ? 1.0f : -1.0f;
      float qs  = (sel==0) ? SC2 : 1.0f;
      #pragma unroll
      for(int mi=0;mi<4;mi++){
        int m = m0 + wm*64 + mi*16 + g*4;
        int b = m>>11, l = m&(SEQ-1);
        if(sel<2){
          // fused RoPE: v = C[l+r][d], partner p = C[l+r][d^1] from lane^1.
          u16* dst = (sel==0?Qb:Kb) + ((size_t)((b*NHEADS+head)*SEQ + l))*DHEAD + d;
          #pragma unroll
          for(int r=0;r<4;r++){
            float v = acc[mi][ni][r];
            float p = __shfl_xor(v, 1);
            float2 t2 = Tab[(size_t)(l+r)*32 + jj];
            float o = (v*t2.x + sgn*(p*t2.y)) * qs;
            dst[(size_t)r*DHEAD] = f2bf(o);
          }
        } else {
          ushort4 pk;
          pk.x=f2bf(acc[mi][ni][0]); pk.y=f2bf(acc[mi][ni][1]);
          pk.z=f2bf(acc[mi][ni][2]); pk.w=f2bf(acc[mi][ni][3]);
          *(ushort4*)(&Vtb[((size_t)((b*NHEADS+head)*DHEAD + d))*SEQ + l]) = pk;
        }
      }
    }
  }
}

// ---------------- Flash attention: 8-wave LDS-shared K/V, 4-deep counted-vmcnt pipeline ----------------
// (r10/r13 winner.) r14 change: T5 s_setprio(1) around the pure-MFMA clusters
// (QKS32, PVM32). attn has wave role-diversity (staging split + per-wave strip
// stagger) -> scheduler can favor MFMA-entering waves (m191: +4-7% attn).

#define QKS32(QF) { \
  f32x16 z_ = {}; \
  __builtin_amdgcn_s_setprio(1); \
  z_ = __builtin_amdgcn_mfma_f32_32x32x16_bf16(kf[0], QF[0], z_, 0,0,0); \
  z_ = __builtin_amdgcn_mfma_f32_32x32x16_bf16(kf[1], QF[1], z_, 0,0,0); \
  z_ = __builtin_amdgcn_mfma_f32_32x32x16_bf16(kf[2], QF[2], z_, 0,0,0); \
  z_ = __builtin_amdgcn_mfma_f32_32x32x16_bf16(kf[3], QF[3], z_, 0,0,0); \
  __builtin_amdgcn_s_setprio(0); \
  sc = z_; }

#define LDK { \
  _Pragma("unroll") for(int dk_=0;dk_<4;dk_++){ \
    int kb_ = (c32*128 + dk_*32 + hl*16) ^ ((c32&7)<<4); \
    kf[dk_] = *(const bf16x8*)((const char*)(&Kls[cur][0]) + kb_); } }

#define LDV { \
  _Pragma("unroll") for(int dt_=0;dt_<2;dt_++) \
    _Pragma("unroll") for(int ks_=0;ks_<2;ks_++){ \
      int d_ = dt_*32 + c32; \
      int vb_ = (d_*64 + ks_*32 + hl*16) ^ (((d_>>1)&7)<<4); \
      vf[dt_][ks_] = *(const bf16x8*)((const char*)(&Vls[cur][0]) + vb_); } }

#define EXPPACK(MASKED, LROW) { \
  unsigned int pk_[8]; \
  _Pragma("unroll") for(int j_=0;j_<8;j_++){ \
    float a_ = fexp2(sc[2*j_]); \
    float b_ = fexp2(sc[2*j_+1]); \
    if(MASKED){ \
      int k0_ = ((2*j_)&3)   + 8*((2*j_)>>2)   + 4*hl; \
      int k1_ = ((2*j_+1)&3) + 8*((2*j_+1)>>2) + 4*hl; \
      a_ = (k0_ <= c32) ? a_ : 0.f; \
      b_ = (k1_ <= c32) ? b_ : 0.f; } \
    LROW += a_ + b_; \
    asm("v_cvt_pk_bf16_f32 %0, %1, %2" : "=v"(pk_[j_]) : "v"(a_), "v"(b_)); } \
  plswap(pk_[0], pk_[2]); \
  plswap(pk_[1], pk_[3]); \
  plswap(pk_[4], pk_[6]); \
  plswap(pk_[5], pk_[7]); \
  u32x4 wa_ = { pk_[0], pk_[1], pk_[2], pk_[3] }; \
  u32x4 wb_ = { pk_[4], pk_[5], pk_[6], pk_[7] }; \
  pa0 = __builtin_bit_cast(bf16x8, wa_); \
  pa1 = __builtin_bit_cast(bf16x8, wb_); }

#define PVM32(O0, O1) { \
  __builtin_amdgcn_s_setprio(1); \
  O0 = __builtin_amdgcn_mfma_f32_32x32x16_bf16(pa0, vf[0][0], O0, 0,0,0); \
  O0 = __builtin_amdgcn_mfma_f32_32x32x16_bf16(pa1, vf[0][1], O0, 0,0,0); \
  O1 = __builtin_amdgcn_mfma_f32_32x32x16_bf16(pa0, vf[1][0], O1, 0,0,0); \
  O1 = __builtin_amdgcn_mfma_f32_32x32x16_bf16(pa1, vf[1][1], O1, 0,0,0); \
  __builtin_amdgcn_s_setprio(0); }

#define STAGE(TILE, BUF) { \
  u16* dst_ = isK ? &Kls[BUF][cch*8] : &Vls[BUF][cch*8]; \
  async_cp16(sbase + soff0 + (size_t)(TILE)*sstep, dst_); }

__global__ __launch_bounds__(512, 2) void attn_kernel(const u16* __restrict__ Q, const u16* __restrict__ Kb,
    const u16* __restrict__ Vt, u16* __restrict__ O){
  __shared__ u16 Kls[4][2048];   // K tile [32 rows][64 d], swizzle-stored, 4-deep
  __shared__ u16 Vls[4][2048];   // Vt tile [64 d][32 l], swizzle-stored, 4-deep
  __shared__ float LsA[8][32];   // per-wave row sums, strip A
  __shared__ float LsB[8][32];   // per-wave row sums, strip B
  int t = threadIdx.x, lane = t&63, w = t>>6;
  int c32 = lane&31, hl = lane>>5, h8 = hl*8;
  int bh = blockIdx.x;
  int b = bh>>4, hh = bh&15;
  int y = blockIdx.y;            // 0..3; y=0 dispatched first = longest (NT=64)
  int sA = 8*y + w;              // 0..31
  int sB = 63 - 8*y - w;         // 32..63  (per-wave work = 65 tiles, uniform)
  int NT = 64 - 8*y;             // block stages tiles 0..NT-1 (NT >= 40 > depth)
  const u16* Qp = Q  + (size_t)bh*SEQ*DHEAD;
  const u16* Kp = Kb + (size_t)bh*SEQ*DHEAD;
  const u16* Vp = Vt + (size_t)bh*DHEAD*SEQ;

  // ---- staging role: waves 0-3 stage K (chunks 0..255), waves 4-7 stage V ----
  bool isK = (w < 4);
  int cch = isK ? t : (t - 256);   // 0..255
  int prow = cch>>3;
  int jsrc = (cch&7) ^ (prow&7);
  size_t soff0, sstep;
  if(isK){
    soff0 = (size_t)prow*64 + (size_t)jsrc*8;
    sstep = 32*64;
  } else {
    int c2 = prow*8 + jsrc;
    soff0 = (size_t)(c2>>2)*SEQ + (size_t)(c2&3)*8;
    sstep = 32;
  }
  const u16* sbase = isK ? Kp : Vp;

  // Q as B-frags for both strips: lane holds Q[wrow + c32][dk*16 + h8 .. +7]
  bf16x8 qfA[4], qfB[4];
  #pragma unroll
  for(int dk=0;dk<4;dk++){
    qfA[dk] = *(const bf16x8*)(&Qp[(size_t)(sA*32 + c32)*DHEAD + dk*16 + h8]);
    qfB[dk] = *(const bf16x8*)(&Qp[(size_t)(sB*32 + c32)*DHEAD + dk*16 + h8]);
  }

  f32x16 oaccA0 = {}, oaccA1 = {}, oaccB0 = {}, oaccB1 = {};
  float lrowA = 0.f, lrowB = 0.f;
  f32x16 sc;
  bf16x8 kf[4], vf[2][2], pa0, pa1;

  // prologue: stage tiles 0..2 into bufs 0..2 (1 load/thread/tile)
  STAGE(0, 0);
  STAGE(1, 1);
  STAGE(2, 2);

  #pragma unroll 1
  for(int tt=0; tt<NT; ++tt){
    // complete the oldest load (tile tt); keep 2 tiles in flight across the barrier
    asm volatile("s_waitcnt vmcnt(2)" ::: "memory");
    asm volatile("s_barrier" ::: "memory");
    // stage tile tt+3 into buf (tt+3)&3 = buf (tt-1)&3: WAR-safe (all waves past
    // compute(tt-1) at the barrier above; DMA write lands after issue).
    if(tt+3 < NT){ STAGE(tt+3, (tt+3)&3); }
    int cur = tt&3;
    if(tt <= sB){
      LDK; LDV;
      QKS32(qfB);
      if(tt == sB){ EXPPACK(1, lrowB); } else { EXPPACK(0, lrowB); }
      PVM32(oaccB0, oaccB1);
      if(tt <= sA){
        QKS32(qfA);
        if(tt == sA){ EXPPACK(1, lrowA); } else { EXPPACK(0, lrowA); }
        PVM32(oaccA0, oaccA1);
      }
    }
  }

  // ---- epilogue: combine k-half sums, broadcast via tiny LDS, write both strips ----
  float lrA = lrowA + __shfl_xor(lrowA, 32);
  float lrB = lrowB + __shfl_xor(lrowB, 32);
  __syncthreads();
  if(hl==0){ LsA[w][c32] = lrA; LsB[w][c32] = lrB; }
  __syncthreads();
  #pragma unroll
  for(int r=0;r<16;r++){
    int row = (r&3)+8*(r>>2)+4*hl;
    float livA = 1.0f/LsA[w][row];
    float livB = 1.0f/LsB[w][row];
    size_t oA = ((size_t)(b*SEQ + sA*32 + row))*DMODEL + hh*DHEAD;
    size_t oB = ((size_t)(b*SEQ + sB*32 + row))*DMODEL + hh*DHEAD;
    O[oA + c32]      = f2bf(oaccA0[r]*livA);
    O[oA + 32 + c32] = f2bf(oaccA1[r]*livA);
    O[oB + c32]      = f2bf(oaccB0[r]*livB);
    O[oB + 32 + c32] = f2bf(oaccB1[r]*livB);
  }
}

// ---------------- launch ----------------
extern "C" void kernel_launch(void* const* d_in, const int* in_sizes, int n_in,
                              void* d_out, int out_size, void* d_ws, size_t ws_size,
                              hipStream_t stream){
  const float* x    = (const float*)d_in[0];
  const float* W_in = (const float*)d_in[1];
  const float* W_o  = (const float*)d_in[2];
  u16* ws = (u16*)d_ws;
  const size_t T16 = (size_t)8*1024*1024;  // 8M bf16 elems = 16 MB per tensor
  u16* h   = ws;            // [8192][1024] bf16
  u16* Qb  = ws +   T16;    // [64][2048][64]
  u16* Kb  = ws + 2*T16;    // [64][2048][64]
  u16* Vtb = ws + 3*T16;    // [64][64][2048]  (V transposed)
  u16* Wb  = ws + 4*T16;    // W_in bf16 [3072][1024]
  u16* Wob = Wb + (size_t)3*DMODEL*DMODEL; // W_o bf16 [1024][1024]
  float2* Tab = (float2*)(Wob + (size_t)DMODEL*DMODEL); // RoPE table [SEQ][32] (cos,sin)
  u16* Ob  = h;             // reuse: h dead after gemm1
  float* out = (float*)d_out;

  const int na4 = 3*DMODEL*DMODEL/4;  // W_in float4 count
  const int nb4 = DMODEL*DMODEL/4;
  const int ncast = na4 + nb4 + SEQ*32;
  const int ncb = (ncast + 255)/256;
  prep_kernel<<<dim3(MROWS + ncb), dim3(256), 0, stream>>>(x, h, W_in, Wb, W_o, Wob, na4, nb4, Tab);
  gemm_bt<0><<<dim3(3*DMODEL/BN, MROWS/BM), dim3(256), 0, stream>>>(
      h, Wb, Qb, Kb, Vtb, nullptr, (const float2*)Tab, MROWS, 3*DMODEL, DMODEL);
  attn_kernel<<<dim3(BHTOT, 4), dim3(512), 0, stream>>>(Qb, Kb, Vtb, Ob);
  gemm_bt<1><<<dim3(DMODEL/BN, MROWS/BM), dim3(256), 0, stream>>>(
      Ob, Wob, nullptr, nullptr, nullptr, out, nullptr, MROWS, DMODEL, DMODEL);
}